// Round 7
// baseline (367.825 us; speedup 1.0000x reference)
//
#include <hip/hip_runtime.h>

typedef _Float16 f16;
typedef f16 f16x8 __attribute__((ext_vector_type(8)));
typedef float f32x16 __attribute__((ext_vector_type(16)));
typedef float f32x4v __attribute__((ext_vector_type(4)));

#define IMG_H 1024
#define IMG_W 1024
#define CIN 64
#define COUT_ 64
#define NBLK 32
#define NACT 512
#define EPS_ 1e-3f

#define WT_ELEMS (36 * 2 * 64 * 8)   // 36864 f16 fragments
#define WT_WGS   144                 // 144*256 == WT_ELEMS
#define FLAGS_OFF (WT_ELEMS * 2)

// Weight fragments for mfma_f32_32x32x16_f16 (lane layout verified R2/R5):
//   kstep ks = tap*4 + q ; lane l elem j: k=(l>>5)*8+j -> cin = q*16+(l>>5)*8+j
//   m/col = l&31 -> cout = ch*32 + (l&31)
__global__ void prep_k(const float* __restrict__ w, const int* __restrict__ abi,
                       f16* __restrict__ wt, int* __restrict__ flags) {
    int wg = blockIdx.x;
    if (wg == WT_WGS) {
        int tid = threadIdx.x;
        for (int i = tid; i < NBLK * NBLK; i += 256) flags[i] = 0;
        __syncthreads();
        for (int t = tid; t < NACT; t += 256) {
            int bi = abi[3 * t + 1];
            int bj = abi[3 * t + 2];
            flags[bi * NBLK + bj] = 1;
        }
        return;
    }
    int t = wg * 256 + threadIdx.x;
    int j  = t & 7;
    int l  = (t >> 3) & 63;
    int ch = (t >> 9) & 1;
    int ks = t >> 10;                 // 0..35
    int tap = ks >> 2, q = ks & 3;
    int ky = tap / 3, kx = tap % 3;
    int cin  = q * 16 + ((l >> 5) << 3) + j;
    int cout = ch * 32 + (l & 31);
    wt[t] = (f16)w[((ky * 3 + kx) * CIN + cin) * COUT_ + cout];
}

__launch_bounds__(256, 3)
__global__ void fused_k(const float* __restrict__ inp,
                        const f16*  __restrict__ wt,
                        const float* __restrict__ cb,
                        const float* __restrict__ gamma,
                        const float* __restrict__ beta,
                        const float* __restrict__ rmean,
                        const float* __restrict__ rvar,
                        const int*  __restrict__ abi,
                        const int*  __restrict__ flags,
                        float* __restrict__ out) {
    // patch window: 10 rows x 34 cols x 8 channel-groups of 16B, XOR-swizzled
    __shared__ uint4 lds[10 * 34 * 8];   // 43520 B -> 3 wg/CU
    __shared__ float scs[64], shs[64];

    const int wg  = blockIdx.x;
    const int tid = threadIdx.x;

    if (wg >= 2 * NACT) {
        // ---- zero-duty (tail of grid): one wg per (bi,bj); zero if inactive ----
        int b = wg - 2 * NACT;
        if (flags[b]) return;
        int bi = b >> 5, bj = b & 31;
        float4 z = make_float4(0.f, 0.f, 0.f, 0.f);
        float4* base = (float4*)(out + ((size_t)(bi * 32) * IMG_W + bj * 32) * COUT_);
        for (int it = tid; it < 32 * 512; it += 256) {
            int r  = it >> 9;
            int c4 = it & 511;
            base[(size_t)r * (IMG_W * COUT_ / 4) + c4] = z;
        }
        return;
    }

    // ---- conv duty: one wg per half-block (16 rows x 32 cols), two row-passes ----
    const int ci = wg;
    const int ab = ci >> 1, yh = ci & 1;
    const int bi = abi[3 * ab + 1];
    const int bj = abi[3 * ab + 2];
    const int lane = tid & 63;
    const int wv   = tid >> 6;
    const int rg2  = wv & 1;       // 4-row group within pass
    const int chh  = wv >> 1;      // cout half

    // BN scale/shift table (64 couts)
    if (tid < 64) {
        float sc = gamma[tid] * rsqrtf(rvar[tid] + EPS_);
        scs[tid] = sc;
        shs[tid] = cb[tid] * sc + beta[tid] - rmean[tid] * sc;
    }

    // per-wave weight fragments (cout half chh): 36 x 4 VGPRs
    f16x8 wf[36];
    const uint4* wt4 = (const uint4*)wt;
    #pragma unroll
    for (int ks = 0; ks < 36; ++ks)
        wf[ks] = __builtin_bit_cast(f16x8, wt4[(ks * 2 + chh) * 64 + lane]);

    const int r0 = bi * 32 + yh * 16 - 1;   // unpadded top halo row
    const int c0 = bj * 32 - 1;
    const int px = lane & 31;
    const int hi = lane >> 5;
    float* outb = out + (((size_t)(bi * 32 + yh * 16) * IMG_W) + bj * 32 + px) * COUT_
                      + chh * 32 + hi * 4;

    for (int pass = 0; pass < 2; ++pass) {
        if (pass) __syncthreads();    // previous k-loop must finish before overwrite

        // stage rows pass*8 .. pass*8+9 into buffer rows 0..9
        for (int task = tid; task < 10 * 34 * 8; task += 256) {
            int g  = task & 7;
            int p  = task >> 3;
            int drl = p / 34;
            int dc  = p - drl * 34;
            int row = r0 + pass * 8 + drl, col = c0 + dc;
            float4 a = make_float4(0.f, 0.f, 0.f, 0.f), b = a;
            if ((unsigned)row < IMG_H && (unsigned)col < IMG_W) {
                const float4* src = (const float4*)(inp + (((size_t)row * IMG_W + col) * CIN + g * 8));
                a = src[0]; b = src[1];
            }
            f16x8 v;
            v[0] = (f16)a.x; v[1] = (f16)a.y; v[2] = (f16)a.z; v[3] = (f16)a.w;
            v[4] = (f16)b.x; v[5] = (f16)b.y; v[6] = (f16)b.z; v[7] = (f16)b.w;
            lds[(p << 3) + (g ^ (dc & 7))] = __builtin_bit_cast(uint4, v);
        }
        __syncthreads();

        for (int yr = 0; yr < 4; ++yr) {
            const int drb = rg2 * 4 + yr;        // local buffer row for ky=0
            const int R   = pass * 8 + drb;      // output row within 16-row tile
            f32x16 accA = {0.f,0.f,0.f,0.f,0.f,0.f,0.f,0.f,0.f,0.f,0.f,0.f,0.f,0.f,0.f,0.f};
            f32x16 accB = {0.f,0.f,0.f,0.f,0.f,0.f,0.f,0.f,0.f,0.f,0.f,0.f,0.f,0.f,0.f,0.f};
            #pragma unroll
            for (int ks = 0; ks < 36; ++ks) {
                const int tap = ks >> 2, q = ks & 3;
                const int ky = tap / 3, kx = tap % 3;
                const int dr = drb + ky;
                const int dc = px + kx;
                const int slot = (q * 2 + hi) ^ (dc & 7);
                uint4 a = lds[((dr * 34 + dc) << 3) + slot];
                if (ks & 1)
                    accB = __builtin_amdgcn_mfma_f32_32x32x16_f16(wf[ks], __builtin_bit_cast(f16x8, a), accB, 0, 0, 0);
                else
                    accA = __builtin_amdgcn_mfma_f32_32x32x16_f16(wf[ks], __builtin_bit_cast(f16x8, a), accA, 0, 0, 0);
            }
            #pragma unroll
            for (int g4 = 0; g4 < 4; ++g4) {
                const int cbase = chh * 32 + g4 * 8 + hi * 4;
                f32x4v sv = *(const f32x4v*)&scs[cbase];
                f32x4v hv = *(const f32x4v*)&shs[cbase];
                f32x4v v;
                #pragma unroll
                for (int u = 0; u < 4; ++u) {
                    float x = (accA[4 * g4 + u] + accB[4 * g4 + u]) * sv[u] + hv[u];
                    v[u] = fmaxf(x, 0.f);
                }
                *(f32x4v*)(outb + (size_t)R * IMG_W * COUT_ + g4 * 8) = v;
            }
        }
    }
}

extern "C" void kernel_launch(void* const* d_in, const int* in_sizes, int n_in,
                              void* d_out, int out_size, void* d_ws, size_t ws_size,
                              hipStream_t stream) {
    const float* inp   = (const float*)d_in[0];
    const float* convw = (const float*)d_in[1];
    const float* convb = (const float*)d_in[2];
    const float* gamma = (const float*)d_in[3];
    const float* beta  = (const float*)d_in[4];
    const float* rmean = (const float*)d_in[5];
    const float* rvar  = (const float*)d_in[6];
    const int*   abi   = (const int*)d_in[7];
    float* out = (float*)d_out;

    f16* wt    = (f16*)d_ws;
    int* flags = (int*)((char*)d_ws + FLAGS_OFF);

    hipLaunchKernelGGL(prep_k, dim3(WT_WGS + 1), dim3(256), 0, stream, convw, abi, wt, flags);
    hipLaunchKernelGGL(fused_k, dim3(2 * NACT + NBLK * NBLK), dim3(256), 0, stream,
                       inp, wt, convb, gamma, beta, rmean, rvar, abi, flags, out);
}

// Round 9
// 118.390 us; speedup vs baseline: 3.1069x; 3.1069x over previous
//
#include <hip/hip_runtime.h>

typedef _Float16 f16;
typedef f16 f16x8 __attribute__((ext_vector_type(8)));
typedef float f32x4 __attribute__((ext_vector_type(4)));

#define IMG_H 1024
#define IMG_W 1024
#define CIN 64
#define COUT_ 64
#define NBLK 32
#define NACT 512
#define EPS_ 1e-3f

#define WT_ELEMS (18 * 4 * 64 * 8)   // 36864 f16 fragments
#define WT_WGS   144                 // 144*256 == WT_ELEMS
#define FLAGS_OFF (WT_ELEMS * 2)

// Weight fragments for mfma_f32_16x16x32_f16 (layout verified R1; same bytes
// serve as A-operand with m=cout, since A/B lane layouts coincide — proven on
// HW for 32x32 in R5):
//   kk = (ky*3+kx)*2 + half ; lane l elem j: k=(l>>4)*8+j -> cin = half*32+(l>>4)*8+j
//   m/col = l&15 -> cout = wv*16 + (l&15)
__global__ void prep_k(const float* __restrict__ w, const int* __restrict__ abi,
                       f16* __restrict__ wt, int* __restrict__ flags) {
    int wg = blockIdx.x;
    if (wg == WT_WGS) {
        int tid = threadIdx.x;
        for (int i = tid; i < NBLK * NBLK; i += 256) flags[i] = 0;
        __syncthreads();
        for (int t = tid; t < NACT; t += 256) {
            int bi = abi[3 * t + 1];
            int bj = abi[3 * t + 2];
            flags[bi * NBLK + bj] = 1;
        }
        return;
    }
    int t = wg * 256 + threadIdx.x;
    int j  = t & 7;
    int l  = (t >> 3) & 63;
    int wv = (t >> 9) & 3;
    int kk = t >> 11;                 // 0..17
    int ky = kk / 6;
    int kx = (kk % 6) >> 1;
    int hf = kk & 1;
    int cin  = hf * 32 + ((l >> 4) << 3) + j;
    int cout = wv * 16 + (l & 15);
    wt[t] = (f16)w[((ky * 3 + kx) * CIN + cin) * COUT_ + cout];
}

__launch_bounds__(256, 3)
__global__ void fused_k(const float* __restrict__ inp,
                        const f16*  __restrict__ wt,
                        const float* __restrict__ cb,
                        const float* __restrict__ gamma,
                        const float* __restrict__ beta,
                        const float* __restrict__ rmean,
                        const float* __restrict__ rvar,
                        const int*  __restrict__ abi,
                        const int*  __restrict__ flags,
                        float* __restrict__ out) {
    // patch window: 10 rows x 34 cols x 8 channel-groups of 16B, XOR-swizzled
    __shared__ uint4 lds[10 * 34 * 8];   // 43520 B -> 3 wg/CU
    __shared__ float scs[64], shs[64];

    const int wg  = blockIdx.x;
    const int tid = threadIdx.x;

    if (wg >= 2 * NACT) {
        // ---- zero-duty (tail of grid): one wg per (bi,bj); zero if inactive ----
        int b = wg - 2 * NACT;
        if (flags[b]) return;
        int bi = b >> 5, bj = b & 31;
        float4 z = make_float4(0.f, 0.f, 0.f, 0.f);
        float4* base = (float4*)(out + ((size_t)(bi * 32) * IMG_W + bj * 32) * COUT_);
        for (int it = tid; it < 32 * 512; it += 256) {
            int r  = it >> 9;
            int c4 = it & 511;
            base[(size_t)r * (IMG_W * COUT_ / 4) + c4] = z;
        }
        return;
    }

    // ---- conv duty: one wg per half-block (16 rows x 32 cols), two row-passes ----
    const int ab = wg >> 1, yh = wg & 1;
    const int bi = abi[3 * ab + 1];
    const int bj = abi[3 * ab + 2];
    const int lane = tid & 63;
    const int wv   = tid >> 6;      // wave owns couts [wv*16, wv*16+16)

    // BN scale/shift table (64 couts)
    if (tid < 64) {
        float sc = gamma[tid] * rsqrtf(rvar[tid] + EPS_);
        scs[tid] = sc;
        shs[tid] = cb[tid] * sc + beta[tid] - rmean[tid] * sc;
    }

    // per-wave weight fragments: 18 x 4 VGPRs = 72 regs
    f16x8 wf[18];
    const uint4* wt4 = (const uint4*)wt;
    #pragma unroll
    for (int kk = 0; kk < 18; ++kk)
        wf[kk] = __builtin_bit_cast(f16x8, wt4[(kk * 4 + wv) * 64 + lane]);

    const int r0 = bi * 32 + yh * 16 - 1;   // unpadded top halo row
    const int c0 = bj * 32 - 1;
    const int px   = lane & 15;    // B col = output pixel column (within half)
    const int kgrp = lane >> 4;    // k sub-group
    const int cob  = wv * 16 + kgrp * 4;   // 4 consecutive couts per lane

    float* outb = out + (((size_t)(bi * 32 + yh * 16) * IMG_W) + bj * 32) * COUT_ + cob;

    for (int pass = 0; pass < 2; ++pass) {
        if (pass) __syncthreads();    // previous k-loop must finish before overwrite

        // stage rows pass*8 .. pass*8+9 into buffer rows 0..9
        for (int task = tid; task < 10 * 34 * 8; task += 256) {
            int g  = task & 7;
            int p  = task >> 3;
            int drl = p / 34;
            int dc  = p - drl * 34;
            int row = r0 + pass * 8 + drl, col = c0 + dc;
            float4 a = make_float4(0.f, 0.f, 0.f, 0.f), b = a;
            if ((unsigned)row < IMG_H && (unsigned)col < IMG_W) {
                const float4* src = (const float4*)(inp + (((size_t)row * IMG_W + col) * CIN + g * 8));
                a = src[0]; b = src[1];
            }
            f16x8 v;
            v[0] = (f16)a.x; v[1] = (f16)a.y; v[2] = (f16)a.z; v[3] = (f16)a.w;
            v[4] = (f16)b.x; v[5] = (f16)b.y; v[6] = (f16)b.z; v[7] = (f16)b.w;
            lds[(p << 3) + (g ^ (dc & 7))] = __builtin_bit_cast(uint4, v);
        }
        __syncthreads();

        // BN tables valid only after the barrier above (written by tid<64)
        const f32x4 sv = *(const f32x4*)&scs[cob];
        const f32x4 hv = *(const f32x4*)&shs[cob];

        for (int yr = 0; yr < 8; ++yr) {
            const int R = pass * 8 + yr;        // output row within 16-row tile
            f32x4 acc0 = {0.f, 0.f, 0.f, 0.f};
            f32x4 acc1 = {0.f, 0.f, 0.f, 0.f};
            #pragma unroll
            for (int kk = 0; kk < 18; ++kk) {
                const int tap = kk >> 1, q = kk & 1;
                const int ky = tap / 3, kx = tap % 3;
                const int dr = yr + ky;
                const int g  = q * 4 + kgrp;
                const int dc0 = px + kx;
                const int dc1 = px + kx + 16;
                uint4 a0 = lds[((dr * 34 + dc0) << 3) + (g ^ (dc0 & 7))];
                uint4 a1 = lds[((dr * 34 + dc1) << 3) + (g ^ (dc1 & 7))];
                acc0 = __builtin_amdgcn_mfma_f32_16x16x32_f16(wf[kk], __builtin_bit_cast(f16x8, a0), acc0, 0, 0, 0);
                acc1 = __builtin_amdgcn_mfma_f32_16x16x32_f16(wf[kk], __builtin_bit_cast(f16x8, a1), acc1, 0, 0, 0);
            }
            // D layout: col = lane&15 = pixel, row = kgrp*4 + r = cout_local
            f32x4 v0, v1;
            #pragma unroll
            for (int r = 0; r < 4; ++r) {
                v0[r] = fmaxf(acc0[r] * sv[r] + hv[r], 0.f);
                v1[r] = fmaxf(acc1[r] * sv[r] + hv[r], 0.f);
            }
            *(f32x4*)(outb + ((size_t)R * IMG_W + px) * COUT_) = v0;
            *(f32x4*)(outb + ((size_t)R * IMG_W + px + 16) * COUT_) = v1;
        }
    }
}

extern "C" void kernel_launch(void* const* d_in, const int* in_sizes, int n_in,
                              void* d_out, int out_size, void* d_ws, size_t ws_size,
                              hipStream_t stream) {
    const float* inp   = (const float*)d_in[0];
    const float* convw = (const float*)d_in[1];
    const float* convb = (const float*)d_in[2];
    const float* gamma = (const float*)d_in[3];
    const float* beta  = (const float*)d_in[4];
    const float* rmean = (const float*)d_in[5];
    const float* rvar  = (const float*)d_in[6];
    const int*   abi   = (const int*)d_in[7];
    float* out = (float*)d_out;

    f16* wt    = (f16*)d_ws;
    int* flags = (int*)((char*)d_ws + FLAGS_OFF);

    hipLaunchKernelGGL(prep_k, dim3(WT_WGS + 1), dim3(256), 0, stream, convw, abi, wt, flags);
    hipLaunchKernelGGL(fused_k, dim3(2 * NACT + NBLK * NBLK), dim3(256), 0, stream,
                       inp, wt, convb, gamma, beta, rmean, rvar, abi, flags, out);
}

// Round 10
// 111.557 us; speedup vs baseline: 3.2972x; 1.0613x over previous
//
#include <hip/hip_runtime.h>

typedef _Float16 f16;
typedef f16 f16x8 __attribute__((ext_vector_type(8)));
typedef float f32x16 __attribute__((ext_vector_type(16)));
typedef float f32x4v __attribute__((ext_vector_type(4)));

#define IMG_H 1024
#define IMG_W 1024
#define CIN 64
#define COUT_ 64
#define NBLK 32
#define NACT 512
#define EPS_ 1e-3f

#define WT_ELEMS (36 * 2 * 64 * 8)   // 36864 f16 fragments
#define WT_WGS   144                 // 144*256 == WT_ELEMS
#define ILIST_OFF (WT_ELEMS * 2)     // int ilist[1024]
#define ICNT_OFF  (ILIST_OFF + 1024 * 4)

// Weight fragments for mfma_f32_32x32x16_f16 (lane layout verified R2/R5/R6):
//   kstep ks = tap*4 + q ; lane l elem j: k=(l>>5)*8+j -> cin = q*16+(l>>5)*8+j
//   m/col = l&31 -> cout = ch*32 + (l&31)
__global__ void prep_k(const float* __restrict__ w, const int* __restrict__ abi,
                       f16* __restrict__ wt, int* __restrict__ ilist,
                       int* __restrict__ icnt) {
    int wg = blockIdx.x;
    int tid = threadIdx.x;
    if (wg == WT_WGS) {
        // build compacted list of inactive blocks
        __shared__ int flg[NBLK * NBLK];
        __shared__ int cnt;
        for (int i = tid; i < NBLK * NBLK; i += 256) flg[i] = 0;
        if (tid == 0) cnt = 0;
        __syncthreads();
        for (int t = tid; t < NACT; t += 256) {
            int bi = abi[3 * t + 1];
            int bj = abi[3 * t + 2];
            flg[bi * NBLK + bj] = 1;
        }
        __syncthreads();
        for (int i = tid; i < NBLK * NBLK; i += 256)
            if (!flg[i]) { int k = atomicAdd(&cnt, 1); ilist[k] = i; }
        __syncthreads();
        if (tid == 0) *icnt = cnt;
        return;
    }
    int t = wg * 256 + tid;
    int j  = t & 7;
    int l  = (t >> 3) & 63;
    int ch = (t >> 9) & 1;
    int ks = t >> 10;                 // 0..35
    int tap = ks >> 2, q = ks & 3;
    int ky = tap / 3, kx = tap % 3;
    int cin  = q * 16 + ((l >> 5) << 3) + j;
    int cout = ch * 32 + (l & 31);
    wt[t] = (f16)w[((ky * 3 + kx) * CIN + cin) * COUT_ + cout];
}

__launch_bounds__(256, 2)
__global__ void fused_k(const float* __restrict__ inp,
                        const f16*  __restrict__ wt,
                        const float* __restrict__ cb,
                        const float* __restrict__ gamma,
                        const float* __restrict__ beta,
                        const float* __restrict__ rmean,
                        const float* __restrict__ rvar,
                        const int*  __restrict__ abi,
                        const int*  __restrict__ ilist,
                        const int*  __restrict__ icnt,
                        float* __restrict__ out) {
    // patch: 18 rows x 34 cols x 8 channel-groups of 16B (f16x8), XOR-swizzled
    __shared__ uint4 lds[18 * 34 * 8];   // 78336 B -> 2 wg/CU
    __shared__ float scs[64], shs[64];

    const int wg  = blockIdx.x;
    const int tid = threadIdx.x;

    // ---- conv duty: one wg per half-block (16 rows x 32 cols) ----
    const int ab = wg >> 1, yh = wg & 1;
    const int bi = abi[3 * ab + 1];
    const int bj = abi[3 * ab + 2];
    const int lane = tid & 63;
    const int wv   = tid >> 6;

    // BN scale/shift table (64 couts)
    if (tid < 64) {
        float sc = gamma[tid] * rsqrtf(rvar[tid] + EPS_);
        scs[tid] = sc;
        shs[tid] = cb[tid] * sc + beta[tid] - rmean[tid] * sc;
    }

    // stage 18x34x64 patch (fp32 -> f16, swizzled channel groups)
    const int r0 = bi * 32 + yh * 16 - 1;
    const int c0 = bj * 32 - 1;
    for (int task = tid; task < 18 * 34 * 8; task += 256) {
        int g  = task & 7;
        int p  = task >> 3;
        int dr = p / 34;
        int dc = p - dr * 34;
        int row = r0 + dr, col = c0 + dc;
        float4 a = make_float4(0.f, 0.f, 0.f, 0.f), b = a;
        if ((unsigned)row < IMG_H && (unsigned)col < IMG_W) {
            const float4* src = (const float4*)(inp + (((size_t)row * IMG_W + col) * CIN + g * 8));
            a = src[0]; b = src[1];
        }
        f16x8 v;
        v[0] = (f16)a.x; v[1] = (f16)a.y; v[2] = (f16)a.z; v[3] = (f16)a.w;
        v[4] = (f16)b.x; v[5] = (f16)b.y; v[6] = (f16)b.z; v[7] = (f16)b.w;
        lds[(p << 3) + (g ^ (dc & 7))] = __builtin_bit_cast(uint4, v);
    }

    // per-wave weight fragments: wave = (row-group rg, cout-half chh)
    const int rg  = wv & 1;
    const int chh = wv >> 1;
    f16x8 wf[36];
    const uint4* wt4 = (const uint4*)wt;
    #pragma unroll
    for (int ks = 0; ks < 36; ++ks)
        wf[ks] = __builtin_bit_cast(f16x8, wt4[(ks * 2 + chh) * 64 + lane]);

    __syncthreads();

    const int px = lane & 31;      // B col = output pixel column
    const int hi = lane >> 5;      // k sub-group
    float* outb = out + (((size_t)(bi * 32 + yh * 16) * IMG_W) + bj * 32 + px) * COUT_
                      + chh * 32 + hi * 4;

    for (int yr = 0; yr < 8; ++yr) {
        const int R = rg * 8 + yr;
        f32x16 accA = {0.f,0.f,0.f,0.f,0.f,0.f,0.f,0.f,0.f,0.f,0.f,0.f,0.f,0.f,0.f,0.f};
        f32x16 accB = {0.f,0.f,0.f,0.f,0.f,0.f,0.f,0.f,0.f,0.f,0.f,0.f,0.f,0.f,0.f,0.f};
        #pragma unroll
        for (int ks = 0; ks < 36; ++ks) {
            const int tap = ks >> 2, q = ks & 3;
            const int ky = tap / 3, kx = tap % 3;
            const int dr = R + ky;
            const int dc = px + kx;
            const int slot = (q * 2 + hi) ^ (dc & 7);
            uint4 a = lds[((dr * 34 + dc) << 3) + slot];
            if (ks & 1)
                accB = __builtin_amdgcn_mfma_f32_32x32x16_f16(wf[ks], __builtin_bit_cast(f16x8, a), accB, 0, 0, 0);
            else
                accA = __builtin_amdgcn_mfma_f32_32x32x16_f16(wf[ks], __builtin_bit_cast(f16x8, a), accA, 0, 0, 0);
        }
        #pragma unroll
        for (int g4 = 0; g4 < 4; ++g4) {
            const int cbase = chh * 32 + g4 * 8 + hi * 4;
            f32x4v sv = *(const f32x4v*)&scs[cbase];
            f32x4v hv = *(const f32x4v*)&shs[cbase];
            f32x4v v;
            #pragma unroll
            for (int u = 0; u < 4; ++u) {
                float x = (accA[4 * g4 + u] + accB[4 * g4 + u]) * sv[u] + hv[u];
                v[u] = fmaxf(x, 0.f);
            }
            *(f32x4v*)(outb + (size_t)R * IMG_W * COUT_ + g4 * 8) = v;
        }
    }

    // ---- distributed zero duty: this wg zeroes half of one inactive block ----
    const int zi = wg >> 1;
    if (zi < *icnt) {
        const int b   = ilist[zi];
        const int zbi = b >> 5, zbj = b & 31;
        const int zh  = wg & 1;
        f32x4v z = {0.f, 0.f, 0.f, 0.f};
        f32x4v* zb = (f32x4v*)(out + ((size_t)(zbi * 32 + zh * 16) * IMG_W + zbj * 32) * COUT_);
        for (int it = tid; it < 16 * 512; it += 256) {
            int r  = it >> 9;               // row within half-block
            int c4 = it & 511;              // float4 within 32*64-float row span
            zb[(size_t)r * (IMG_W * COUT_ / 4) + c4] = z;
        }
    }
}

extern "C" void kernel_launch(void* const* d_in, const int* in_sizes, int n_in,
                              void* d_out, int out_size, void* d_ws, size_t ws_size,
                              hipStream_t stream) {
    const float* inp   = (const float*)d_in[0];
    const float* convw = (const float*)d_in[1];
    const float* convb = (const float*)d_in[2];
    const float* gamma = (const float*)d_in[3];
    const float* beta  = (const float*)d_in[4];
    const float* rmean = (const float*)d_in[5];
    const float* rvar  = (const float*)d_in[6];
    const int*   abi   = (const int*)d_in[7];
    float* out = (float*)d_out;

    f16* wt    = (f16*)d_ws;
    int* ilist = (int*)((char*)d_ws + ILIST_OFF);
    int* icnt  = (int*)((char*)d_ws + ICNT_OFF);

    hipLaunchKernelGGL(prep_k, dim3(WT_WGS + 1), dim3(256), 0, stream, convw, abi, wt, ilist, icnt);
    hipLaunchKernelGGL(fused_k, dim3(2 * NACT), dim3(256), 0, stream,
                       inp, wt, convb, gamma, beta, rmean, rvar, abi, ilist, icnt, out);
}